// Round 7
// baseline (953.113 us; speedup 1.0000x reference)
//
#include <hip/hip_runtime.h>
#include <hip/hip_cooperative_groups.h>
#include <math.h>

namespace cg = cooperative_groups;

#define NEG_INF (-__builtin_inff())

typedef __attribute__((ext_vector_type(8))) short short8;
typedef __attribute__((ext_vector_type(4))) float f32x4;

__device__ __forceinline__ unsigned f2bf(float f) {   // fp32 -> bf16 bits (RNE)
    union { float f; unsigned u; } v; v.f = f;
    return (v.u + 0x7fffu + ((v.u >> 16) & 1u)) >> 16;
}

// ============ pad kernel: x channel -> zero-padded (4,66,66,66) bf16 ============
__global__ __launch_bounds__(256) void pad_kernel(
    const float* __restrict__ img, unsigned short* __restrict__ pad)
{
    int i = blockIdx.x * 256 + threadIdx.x;      // cell within one sample
    if (i >= 66 * 66 * 66) return;
    int b = blockIdx.y;
    int z = i / 4356;
    int rem = i - z * 4356;
    int y = rem / 66;
    int x = rem - y * 66;
    float v = 0.f;
    if (z >= 1 && z <= 64 && y >= 1 && y <= 64 && x >= 1 && x <= 64)
        v = img[((size_t)b << 19) + ((z - 1) << 12) + ((y - 1) << 6) + (x - 1)];
    pad[(size_t)b * 287496 + i] = (unsigned short)f2bf(v);
}

// ============ gate via MFMA: p = sigmoid(sum_c pw[c]*relu(conv(x)+hb[c])) ======
// GEMM: A[m=voxel][k=tap] * B[k][n=channel]; K=27+bias->32; N=150->160.
// Grid 4096 (4 groups/wave) for 8 waves/SIMD offered. bounds(256,4): VGPR<=128
// -- R6's (256,8) forced VGPR=32 and spilled bfrag to scratch (410 MB FETCH).
__global__ __launch_bounds__(256, 4) void gate_mfma(
    const unsigned short* __restrict__ pad,
    const float* __restrict__ hw, const float* __restrict__ hb,
    const float* __restrict__ pw, float* __restrict__ p)
{
    const int lane = threadIdx.x & 63;
    const int col  = lane & 15;
    const int q    = lane >> 4;
    const int W    = blockIdx.x * 4 + (threadIdx.x >> 6);   // 16384 waves

    union BF { int4 i4; short8 s8; };
    BF    bfrag[10];
    float pwv[10];
    #pragma unroll
    for (int t = 0; t < 10; ++t) {
        int c = 16 * t + col;
        bool cv = c < 150;
        unsigned hv[8];
        #pragma unroll
        for (int j = 0; j < 8; ++j) {
            int k = 8 * q + j;
            float wv = 0.f;
            if (cv) {
                if (k < 27) wv = hw[c * 27 + k];
                else if (k == 27) wv = hb[c];
            }
            hv[j] = f2bf(wv);
        }
        bfrag[t].i4 = make_int4(hv[0] | (hv[1] << 16), hv[2] | (hv[3] << 16),
                                hv[4] | (hv[5] << 16), hv[6] | (hv[7] << 16));
        pwv[t] = cv ? pw[c] : 0.f;
    }

    int offL[8]; unsigned cstA[8]; bool ldA[8];
    #pragma unroll
    for (int j = 0; j < 8; ++j) {
        int k = 8 * q + j;
        int dz = (k * 57) >> 9;
        int rem = k - 9 * dz;
        int dy = (rem * 171) >> 9;
        int dx = rem - 3 * dy;
        ldA[j]  = (k < 27);
        offL[j] = (k < 27) ? (dz * 4356 + dy * 66 + dx) : 0;
        cstA[j] = (k == 27) ? 0x3F80u : 0u;
    }

    #pragma unroll
    for (int i = 0; i < 4; ++i) {
        int g   = W * 4 + i;                 // 65536 groups of 16 voxels
        int x0  = (g & 3) << 4;
        int row = g >> 2;
        int y = row & 63, zz = (row >> 6) & 63, b = row >> 12;
        int abase = b * 287496 + zz * 4356 + y * 66 + x0 + col;

        unsigned av[8];
        #pragma unroll
        for (int j = 0; j < 8; ++j) {
            unsigned v = pad[abase + offL[j]];
            av[j] = ldA[j] ? v : cstA[j];
        }
        union { int4 i4; short8 s8; } af;
        af.i4 = make_int4(av[0] | (av[1] << 16), av[2] | (av[3] << 16),
                          av[4] | (av[5] << 16), av[6] | (av[7] << 16));

        const f32x4 zero = {0.f, 0.f, 0.f, 0.f};
        f32x4 rr[10];
        #pragma unroll
        for (int t = 0; t < 10; ++t)
            rr[t] = __builtin_amdgcn_mfma_f32_16x16x32_bf16(af.s8, bfrag[t].s8, zero, 0, 0, 0);

        float ax = 0.f, ay = 0.f, az = 0.f, aw = 0.f;
        #pragma unroll
        for (int t = 0; t < 10; ++t) {
            ax = fmaf(pwv[t], fmaxf(rr[t].x, 0.f), ax);
            ay = fmaf(pwv[t], fmaxf(rr[t].y, 0.f), ay);
            az = fmaf(pwv[t], fmaxf(rr[t].z, 0.f), az);
            aw = fmaf(pwv[t], fmaxf(rr[t].w, 0.f), aw);
        }
        #pragma unroll
        for (int m = 1; m < 16; m <<= 1) {
            ax += __shfl_xor(ax, m);
            ay += __shfl_xor(ay, m);
            az += __shfl_xor(az, m);
            aw += __shfl_xor(aw, m);
        }
        if (col == 0) {
            float4 o;
            o.x = 1.f / (1.f + __expf(-ax));
            o.y = 1.f / (1.f + __expf(-ay));
            o.z = 1.f / (1.f + __expf(-az));
            o.w = 1.f / (1.f + __expf(-aw));
            *(float4*)(p + (b << 18) + (zz << 12) + (y << 6) + x0 + 4 * q) = o;
        }
    }
}

// ============ fused propagation: ONE cooperative kernel, 8 rounds ============
// R6 post-mortem: ~15 us per graph node dominates prop (in-kernel ~8 us). So:
// one hipLaunchCooperativeKernel, rounds separated by grid.sync() (7 syncs)
// instead of 8 kernel launches. Per round: stage 12x16x64 cube (48 KB LDS),
// T in-place iterations with barrier-per-plane, write core to the round's
// output buffer (ping-pong d_out <-> ws).
#define ZC 12
#define YC 16
#define PL 1024   // 16*64 floats per z-plane

#define ROWY(zz_, Q, C) {                                                  \
    const float* pz = S + (zz_) * PL + lbase;                              \
    float4 r0 = *(const float4*)(pz - 64);                                 \
    float4 r1 = *(const float4*)(pz);                                      \
    float4 r2 = *(const float4*)(pz + 64);                                 \
    float4 cm;                                                             \
    cm.x = fmaxf(fmaxf(r0.x, r1.x), r2.x);                                 \
    cm.y = fmaxf(fmaxf(r0.y, r1.y), r2.y);                                 \
    cm.z = fmaxf(fmaxf(r0.z, r1.z), r2.z);                                 \
    cm.w = fmaxf(fmaxf(r0.w, r1.w), r2.w);                                 \
    float lm = __shfl(cm.w, lane - 1);                                     \
    float rm = __shfl(cm.x, lane + 1);                                     \
    if (x4 == 0)  lm = NEG_INF;                                            \
    if (x4 == 15) rm = NEG_INF;                                            \
    Q.x = fmaxf(lm, fmaxf(cm.x, cm.y));                                    \
    Q.y = fmaxf(cm.x, fmaxf(cm.y, cm.z));                                  \
    Q.z = fmaxf(cm.y, fmaxf(cm.z, cm.w));                                  \
    Q.w = fmaxf(fmaxf(cm.z, cm.w), rm);                                    \
    C = r1;                                                                \
}

template<int T>
__device__ __forceinline__ void prop_round(
    const float* __restrict__ vb,   // v input, this sample
    const float* __restrict__ rb,   // r, this sample
    const float* __restrict__ pb,   // p, this sample
    float* __restrict__ ob,         // v output (core region), this sample
    float* __restrict__ S,
    int tz, int ty, int x4, int x0, int yy, int lane)
{
    int gy = ty + yy - 4;
    bool vy = (unsigned)gy < 64u;

    // ---- stage cube
    {
        const float* src = vb + gy * 64 + x0;
        #pragma unroll
        for (int z = 0; z < ZC; ++z) {
            int gz = tz + z - 4;
            float4 v = make_float4(NEG_INF, NEG_INF, NEG_INF, NEG_INF);
            if (vy && ((unsigned)gz < 64u)) v = *(const float4*)(src + (gz << 12));
            *(float4*)(S + z * PL + yy * 64 + x0) = v;
        }
    }
    __syncthreads();

    int lbase = yy * 64 + x0;
    int goff  = gy * 64 + x0;

    #pragma unroll
    for (int it = 0; it < T; ++it) {
        const int lo = 5 - T + it;          // 1..4 for T=4; 3..4 for T=2
        const bool lastit = (it == T - 1);
        bool act = (yy >= lo) && (yy < YC - lo);

        float4 q0, q1, q2, c1, c2, dmy;
        float4 pvc = make_float4(0, 0, 0, 0), rvc = pvc;
        bool vzc = false;
        if (act) {
            ROWY(lo - 1, q0, dmy);
            ROWY(lo,     q1, c1);
            int gz = tz + lo - 4;
            vzc = vy && ((unsigned)gz < 64u);
            if (vzc) {
                int off = (gz << 12) + goff;
                pvc = *(const float4*)(pb + off);
                rvc = *(const float4*)(rb + off);
            }
        }

        #pragma unroll
        for (int z = lo; z < ZC - lo; ++z) {
            float4 vn;
            float4 pvn = make_float4(0, 0, 0, 0), rvn = pvn;
            bool vzn = false;
            if (act) {
                if (z + 1 < ZC - lo) {      // prefetch next plane's p/r
                    int gz1 = tz + z - 3;
                    vzn = vy && ((unsigned)gz1 < 64u);
                    if (vzn) {
                        int off1 = (gz1 << 12) + goff;
                        pvn = *(const float4*)(pb + off1);
                        rvn = *(const float4*)(rb + off1);
                    }
                }
                ROWY(z + 1, q2, c2);
                if (vzc) {
                    int off = ((tz + z - 4) << 12) + goff;
                    float4 m3;
                    m3.x = fmaxf(fmaxf(q0.x, q1.x), q2.x);
                    m3.y = fmaxf(fmaxf(q0.y, q1.y), q2.y);
                    m3.z = fmaxf(fmaxf(q0.z, q1.z), q2.z);
                    m3.w = fmaxf(fmaxf(q0.w, q1.w), q2.w);
                    vn.x = fmaxf(c1.x, fmaf(pvc.x, m3.x - rvc.x, rvc.x));
                    vn.y = fmaxf(c1.y, fmaf(pvc.y, m3.y - rvc.y, rvc.y));
                    vn.z = fmaxf(c1.z, fmaf(pvc.z, m3.z - rvc.z, rvc.z));
                    vn.w = fmaxf(c1.w, fmaf(pvc.w, m3.w - rvc.w, rvc.w));
                    if (lastit) *(float4*)(ob + off) = vn;
                } else {
                    vn = c1;
                }
            }
            __syncthreads();   // separates reads of plane z (step z-1) from this write
            if (act) {
                *(float4*)(S + z * PL + lbase) = vn;
                q0 = q1; q1 = q2; c1 = c2;
                pvc = pvn; rvc = rvn; vzc = vzn;
            }
        }
    }
    __syncthreads();
}

__global__ __launch_bounds__(256, 2) void prop_coop(
    const float* __restrict__ img,    // (4,2,64,64,64)
    const float* __restrict__ pbuf,   // p, sample stride 2^18
    float* __restrict__ bufX,         // = d_out (final round lands here)
    float* __restrict__ bufY)         // ws ping buffer
{
    cg::grid_group grid = cg::this_grid();
    __shared__ float S[ZC * PL];      // 48 KB

    int blk = blockIdx.x;             // 512 blocks
    int g   = ((blk & 7) << 6) | (blk >> 3);   // XCD-slab swizzle
    int b  = g >> 7;
    int tz = ((g >> 3) & 15) << 2;
    int ty = (g & 7) << 3;

    int tid  = threadIdx.x;
    int x4   = tid & 15, x0 = x4 << 2;
    int yy   = tid >> 4;
    int lane = tid & 63;

    const float* rb = img + (1 << 18) + ((size_t)b << 19);  // r channel
    const float* pb = pbuf + ((size_t)b << 18);
    float* X = bufX + ((size_t)b << 18);
    float* Y = bufY + ((size_t)b << 18);

    // round 0: v0 = r -> Y
    prop_round<4>(rb, rb, pb, Y, S, tz, ty, x4, x0, yy, lane);
    __threadfence(); grid.sync();

    // rounds 1..6: alternate Y->X, X->Y
    #pragma unroll 1
    for (int r = 1; r < 7; ++r) {
        const float* vin = (r & 1) ? Y : X;
        float*       vout = (r & 1) ? X : Y;
        prop_round<4>(vin, rb, pb, vout, S, tz, ty, x4, x0, yy, lane);
        __threadfence(); grid.sync();
    }

    // round 7 (T=2): Y -> X = d_out.  4*7 + 2 = 30 iterations total.
    prop_round<2>(Y, rb, pb, X, S, tz, ty, x4, x0, yy, lane);
}

extern "C" void kernel_launch(void* const* d_in, const int* in_sizes, int n_in,
                              void* d_out, int out_size, void* d_ws, size_t ws_size,
                              hipStream_t stream) {
    const float* img = (const float*)d_in[0];   // (4,2,64,64,64)
    const float* hw  = (const float*)d_in[1];   // (150,27)
    const float* hb  = (const float*)d_in[2];   // (150,)
    const float* pw  = (const float*)d_in[3];   // (150,)
    // d_in[4] = k (device scalar); reference fixes k=30.

    float* out = (float*)d_out;                      // X buffer (4 MB)
    float* p   = (float*)d_ws;                       // 4 MB
    float* vA  = (float*)((char*)d_ws + (4u << 20)); // Y buffer (4 MB)
    unsigned short* pad = (unsigned short*)((char*)d_ws + (4u << 20)); // pre-prop only

    pad_kernel<<<dim3(1124, 4), 256, 0, stream>>>(img, pad);
    gate_mfma<<<4096, 256, 0, stream>>>(pad, hw, hb, pw, p);

    const float* imgA = img;
    const float* pA   = p;
    float*       oA   = out;
    float*       yA   = vA;
    void* args[4] = { &imgA, &pA, &oA, &yA };
    hipLaunchCooperativeKernel((void*)prop_coop, dim3(512), dim3(256), args, 0, stream);
}

// Round 8
// 228.859 us; speedup vs baseline: 4.1646x; 4.1646x over previous
//
#include <hip/hip_runtime.h>
#include <math.h>

#define NEG_INF (-__builtin_inff())

typedef __attribute__((ext_vector_type(8))) short short8;
typedef __attribute__((ext_vector_type(4))) float f32x4;

__device__ __forceinline__ unsigned f2bf(float f) {   // fp32 -> bf16 bits (RNE)
    union { float f; unsigned u; } v; v.f = f;
    return (v.u + 0x7fffu + ((v.u >> 16) & 1u)) >> 16;
}

// ============ pad kernel: x channel -> zero-padded (4,66,66,66) bf16 ============
__global__ __launch_bounds__(256) void pad_kernel(
    const float* __restrict__ img, unsigned short* __restrict__ pad)
{
    int i = blockIdx.x * 256 + threadIdx.x;      // cell within one sample
    if (i >= 66 * 66 * 66) return;
    int b = blockIdx.y;
    int z = i / 4356;
    int rem = i - z * 4356;
    int y = rem / 66;
    int x = rem - y * 66;
    float v = 0.f;
    if (z >= 1 && z <= 64 && y >= 1 && y <= 64 && x >= 1 && x <= 64)
        v = img[((size_t)b << 19) + ((z - 1) << 12) + ((y - 1) << 6) + (x - 1)];
    pad[(size_t)b * 287496 + i] = (unsigned short)f2bf(v);
}

// ============ B-fragment prep: per-lane MFMA B frags + pw, stored to global ====
// One wave. Lane (col=lane&15, q=lane>>4) builds bfrag[t]/pwv[t] exactly as the
// gate consumes them; gate then does 10 dwordx4 + 10 dword loads per wave
// instead of ~160 scalar loads + 160 f2bf per wave.
__global__ void bprep_kernel(
    const float* __restrict__ hw, const float* __restrict__ hb,
    const float* __restrict__ pw, int4* __restrict__ wf, float* __restrict__ pv)
{
    int lane = threadIdx.x;          // 0..63
    int col = lane & 15, q = lane >> 4;
    for (int t = 0; t < 10; ++t) {
        int c = 16 * t + col;
        bool cv = c < 150;
        unsigned hv[8];
        #pragma unroll
        for (int j = 0; j < 8; ++j) {
            int k = 8 * q + j;
            float wv = 0.f;
            if (cv) {
                if (k < 27) wv = hw[c * 27 + k];
                else if (k == 27) wv = hb[c];
            }
            hv[j] = f2bf(wv);
        }
        wf[(t << 6) + lane] = make_int4(hv[0] | (hv[1] << 16), hv[2] | (hv[3] << 16),
                                        hv[4] | (hv[5] << 16), hv[6] | (hv[7] << 16));
        pv[(t << 6) + lane] = cv ? pw[c] : 0.f;
    }
}

// ============ gate via MFMA: p = sigmoid(sum_c pw[c]*relu(conv(x)+hb[c])) ======
// GEMM: A[m=voxel][k=tap] * B[k][n=channel]; K=27+bias->32; N=150->160.
// Grid 4096 (4 groups/wave, 8 waves/SIMD offered). bounds(256,4): VGPR<=128 --
// R5 measured VGPR=56 under this; R6's (256,8) forced 32 and spilled (410 MB).
__global__ __launch_bounds__(256, 4) void gate_mfma(
    const unsigned short* __restrict__ pad,
    const int4* __restrict__ wf, const float* __restrict__ pv,
    float* __restrict__ p)
{
    const int lane = threadIdx.x & 63;
    const int col  = lane & 15;
    const int q    = lane >> 4;
    const int W    = blockIdx.x * 4 + (threadIdx.x >> 6);   // 16384 waves

    union BF { int4 i4; short8 s8; };
    BF    bfrag[10];
    float pwv[10];
    #pragma unroll
    for (int t = 0; t < 10; ++t) {
        bfrag[t].i4 = wf[(t << 6) + lane];
        pwv[t]      = pv[(t << 6) + lane];
    }

    int offL[8]; unsigned cstA[8]; bool ldA[8];
    #pragma unroll
    for (int j = 0; j < 8; ++j) {
        int k = 8 * q + j;
        int dz = (k * 57) >> 9;
        int rem = k - 9 * dz;
        int dy = (rem * 171) >> 9;
        int dx = rem - 3 * dy;
        ldA[j]  = (k < 27);
        offL[j] = (k < 27) ? (dz * 4356 + dy * 66 + dx) : 0;
        cstA[j] = (k == 27) ? 0x3F80u : 0u;
    }

    #pragma unroll
    for (int i = 0; i < 4; ++i) {
        int g   = W * 4 + i;                 // 65536 groups of 16 voxels
        int x0  = (g & 3) << 4;
        int row = g >> 2;
        int y = row & 63, zz = (row >> 6) & 63, b = row >> 12;
        int abase = b * 287496 + zz * 4356 + y * 66 + x0 + col;

        unsigned av[8];
        #pragma unroll
        for (int j = 0; j < 8; ++j) {
            unsigned v = pad[abase + offL[j]];
            av[j] = ldA[j] ? v : cstA[j];
        }
        union { int4 i4; short8 s8; } af;
        af.i4 = make_int4(av[0] | (av[1] << 16), av[2] | (av[3] << 16),
                          av[4] | (av[5] << 16), av[6] | (av[7] << 16));

        const f32x4 zero = {0.f, 0.f, 0.f, 0.f};
        f32x4 rr[10];
        #pragma unroll
        for (int t = 0; t < 10; ++t)
            rr[t] = __builtin_amdgcn_mfma_f32_16x16x32_bf16(af.s8, bfrag[t].s8, zero, 0, 0, 0);

        float ax = 0.f, ay = 0.f, az = 0.f, aw = 0.f;
        #pragma unroll
        for (int t = 0; t < 10; ++t) {
            ax = fmaf(pwv[t], fmaxf(rr[t].x, 0.f), ax);
            ay = fmaf(pwv[t], fmaxf(rr[t].y, 0.f), ay);
            az = fmaf(pwv[t], fmaxf(rr[t].z, 0.f), az);
            aw = fmaf(pwv[t], fmaxf(rr[t].w, 0.f), aw);
        }
        #pragma unroll
        for (int m = 1; m < 16; m <<= 1) {
            ax += __shfl_xor(ax, m);
            ay += __shfl_xor(ay, m);
            az += __shfl_xor(az, m);
            aw += __shfl_xor(aw, m);
        }
        if (col == 0) {
            float4 o;
            o.x = 1.f / (1.f + __expf(-ax));
            o.y = 1.f / (1.f + __expf(-ay));
            o.z = 1.f / (1.f + __expf(-az));
            o.w = 1.f / (1.f + __expf(-aw));
            *(float4*)(p + (b << 18) + (zz << 12) + (y << 6) + x0 + 4 * q) = o;
        }
    }
}

// ============ fused propagation: in-place LDS cube, barrier-per-plane =========
// (R6 kernel verbatim — measured ~21 us/launch incl. node overhead; R7's
// cooperative merge regressed 4x due to ~100 us grid.sync, reverted.)
#define ZC 12
#define YC 16
#define PL 1024   // 16*64 floats per z-plane

template<int T>
__global__ __launch_bounds__(256, 2) void prop_kernel(
    const float* __restrict__ vin, int sstride,
    const float* __restrict__ rimg,   // r base = img + 2^18, sample stride 2^19
    const float* __restrict__ pbuf,   // p, sample stride 2^18
    float* __restrict__ vout)
{
    __shared__ float S[ZC * PL];
    int blk = blockIdx.x;             // 512 blocks
    int g   = ((blk & 7) << 6) | (blk >> 3);   // XCD-slab swizzle
    int b  = g >> 7;
    int tz = ((g >> 3) & 15) << 2;
    int ty = (g & 7) << 3;

    const float* vb = vin  + (size_t)b * sstride;
    const float* rb = rimg + ((size_t)b << 19);
    const float* pb = pbuf + ((size_t)b << 18);
    float*       ob = vout + ((size_t)b << 18);

    int tid  = threadIdx.x;
    int x4   = tid & 15, x0 = x4 << 2;
    int yy   = tid >> 4;
    int lane = tid & 63;

    int gy = ty + yy - 4;
    bool vy = (unsigned)gy < 64u;

    // ---- stage
    {
        const float* src = vb + gy * 64 + x0;
        #pragma unroll
        for (int z = 0; z < ZC; ++z) {
            int gz = tz + z - 4;
            float4 v = make_float4(NEG_INF, NEG_INF, NEG_INF, NEG_INF);
            if (vy && ((unsigned)gz < 64u)) v = *(const float4*)(src + (gz << 12));
            *(float4*)(S + z * PL + yy * 64 + x0) = v;
        }
    }
    __syncthreads();

    int lbase = yy * 64 + x0;
    int goff  = gy * 64 + x0;

    #define ROWY(zz_, Q, C) {                                                  \
        const float* pz = S + (zz_) * PL + lbase;                              \
        float4 r0 = *(const float4*)(pz - 64);                                 \
        float4 r1 = *(const float4*)(pz);                                      \
        float4 r2 = *(const float4*)(pz + 64);                                 \
        float4 cm;                                                             \
        cm.x = fmaxf(fmaxf(r0.x, r1.x), r2.x);                                 \
        cm.y = fmaxf(fmaxf(r0.y, r1.y), r2.y);                                 \
        cm.z = fmaxf(fmaxf(r0.z, r1.z), r2.z);                                 \
        cm.w = fmaxf(fmaxf(r0.w, r1.w), r2.w);                                 \
        float lm = __shfl(cm.w, lane - 1);                                     \
        float rm = __shfl(cm.x, lane + 1);                                     \
        if (x4 == 0)  lm = NEG_INF;                                            \
        if (x4 == 15) rm = NEG_INF;                                            \
        Q.x = fmaxf(lm, fmaxf(cm.x, cm.y));                                    \
        Q.y = fmaxf(cm.x, fmaxf(cm.y, cm.z));                                  \
        Q.z = fmaxf(cm.y, fmaxf(cm.z, cm.w));                                  \
        Q.w = fmaxf(fmaxf(cm.z, cm.w), rm);                                    \
        C = r1;                                                                \
    }

    #pragma unroll
    for (int it = 0; it < T; ++it) {
        const int lo = 5 - T + it;
        const bool lastit = (it == T - 1);
        bool act = (yy >= lo) && (yy < YC - lo);

        float4 q0, q1, q2, c1, c2, dmy;
        float4 pvc = make_float4(0, 0, 0, 0), rvc = pvc;
        bool vzc = false;
        if (act) {
            ROWY(lo - 1, q0, dmy);
            ROWY(lo,     q1, c1);
            int gz = tz + lo - 4;
            vzc = vy && ((unsigned)gz < 64u);
            if (vzc) {
                int off = (gz << 12) + goff;
                pvc = *(const float4*)(pb + off);
                rvc = *(const float4*)(rb + off);
            }
        }

        #pragma unroll
        for (int z = lo; z < ZC - lo; ++z) {
            float4 vn;
            float4 pvn = make_float4(0, 0, 0, 0), rvn = pvn;
            bool vzn = false;
            if (act) {
                if (z + 1 < ZC - lo) {      // prefetch next plane's p/r
                    int gz1 = tz + z - 3;
                    vzn = vy && ((unsigned)gz1 < 64u);
                    if (vzn) {
                        int off1 = (gz1 << 12) + goff;
                        pvn = *(const float4*)(pb + off1);
                        rvn = *(const float4*)(rb + off1);
                    }
                }
                ROWY(z + 1, q2, c2);
                if (vzc) {
                    int off = ((tz + z - 4) << 12) + goff;
                    float4 m3;
                    m3.x = fmaxf(fmaxf(q0.x, q1.x), q2.x);
                    m3.y = fmaxf(fmaxf(q0.y, q1.y), q2.y);
                    m3.z = fmaxf(fmaxf(q0.z, q1.z), q2.z);
                    m3.w = fmaxf(fmaxf(q0.w, q1.w), q2.w);
                    vn.x = fmaxf(c1.x, fmaf(pvc.x, m3.x - rvc.x, rvc.x));
                    vn.y = fmaxf(c1.y, fmaf(pvc.y, m3.y - rvc.y, rvc.y));
                    vn.z = fmaxf(c1.z, fmaf(pvc.z, m3.z - rvc.z, rvc.z));
                    vn.w = fmaxf(c1.w, fmaf(pvc.w, m3.w - rvc.w, rvc.w));
                    if (lastit) *(float4*)(ob + off) = vn;
                } else {
                    vn = c1;
                }
            }
            __syncthreads();   // separates reads of plane z (step z-1) from this write
            if (act) {
                *(float4*)(S + z * PL + lbase) = vn;
                q0 = q1; q1 = q2; c1 = c2;
                pvc = pvn; rvc = rvn; vzc = vzn;
            }
        }
    }
    #undef ROWY
}

extern "C" void kernel_launch(void* const* d_in, const int* in_sizes, int n_in,
                              void* d_out, int out_size, void* d_ws, size_t ws_size,
                              hipStream_t stream) {
    const float* img = (const float*)d_in[0];   // (4,2,64,64,64)
    const float* hw  = (const float*)d_in[1];   // (150,27)
    const float* hb  = (const float*)d_in[2];   // (150,)
    const float* pw  = (const float*)d_in[3];   // (150,)
    // d_in[4] = k (device scalar); reference fixes k=30.

    float* out = (float*)d_out;                      // X buffer (4 MB)
    float* p   = (float*)d_ws;                       // 4 MB
    float* vA  = (float*)((char*)d_ws + (4u << 20)); // Y buffer (4 MB)
    // pad (2.3 MB) + wf/pv (13 KB) live inside the vA slot; both are fully
    // consumed by gate_mfma before prop round 0 overwrites Y.
    unsigned short* pad = (unsigned short*)((char*)d_ws + (4u << 20));
    int4*  wf = (int4*)((char*)d_ws + 6815744);      // 6.5 MB offset
    float* pv = (float*)((char*)d_ws + 6815744 + 10240);

    bprep_kernel<<<1, 64, 0, stream>>>(hw, hb, pw, wf, pv);
    pad_kernel<<<dim3(1124, 4), 256, 0, stream>>>(img, pad);
    gate_mfma<<<4096, 256, 0, stream>>>(pad, wf, pv, p);

    const float* r0 = img + (1 << 18);  // r channel base, sample stride 2^19

    // 7*T4 + 1*T2 = 30 iterations; ping-pong ends in d_out.
    prop_kernel<4><<<512, 256, 0, stream>>>(r0,  1 << 19, r0, p, vA);   // img -> Y
    prop_kernel<4><<<512, 256, 0, stream>>>(vA,  1 << 18, r0, p, out);  // Y -> X
    prop_kernel<4><<<512, 256, 0, stream>>>(out, 1 << 18, r0, p, vA);
    prop_kernel<4><<<512, 256, 0, stream>>>(vA,  1 << 18, r0, p, out);
    prop_kernel<4><<<512, 256, 0, stream>>>(out, 1 << 18, r0, p, vA);
    prop_kernel<4><<<512, 256, 0, stream>>>(vA,  1 << 18, r0, p, out);
    prop_kernel<4><<<512, 256, 0, stream>>>(out, 1 << 18, r0, p, vA);
    prop_kernel<2><<<512, 256, 0, stream>>>(vA,  1 << 18, r0, p, out);  // -> d_out
}